// Round 19
// baseline (121.396 us; speedup 1.0000x reference)
//
#include <hip/hip_runtime.h>
#include <hip/hip_bf16.h>

typedef float f32x4 __attribute__((ext_vector_type(4)));
typedef float f32x2 __attribute__((ext_vector_type(2)));
typedef short s16x8 __attribute__((ext_vector_type(8)));

__device__ __forceinline__ float leaky2(float x){ return fmaf(0.4f, fabsf(x), 0.6f * x); }

__device__ __forceinline__ short f2bf(float f){
    return __builtin_bit_cast(short, __float2bfloat16(f));
}

// ---------------------------------------------------------------------------
// K_cvt (lite): packs featbf + w1p + ew2p. Block 2048 zeroes accums
// (incl. decf done-counter at [501]) + setup math (A, sparsity, DAG).
// ---------------------------------------------------------------------------
__global__ __launch_bounds__(256) void k_cvt(
    const float* __restrict__ feat, const float* __restrict__ ew1,
    const float* __restrict__ ew2,
    short* __restrict__ featbf, short* __restrict__ w1p,
    short* __restrict__ ew2p,
    const float* __restrict__ lw, float* __restrict__ A,
    float* __restrict__ acc)
{
    if (blockIdx.x >= 2048){
        __shared__ float A2s[1024], mp[1024], red[256];
        const int t = threadIdx.x;
        acc[t] = 0.f;
        acc[t + 256] = 0.f;
        float part = 0.f;
        #pragma unroll
        for (int q = 0; q < 4; ++q){
            int e = t * 4 + q;
            int r = e >> 5, c = e & 31;
            float v = lw[e];
            float sig = 1.f / (1.f + expf(-v));
            float l2 = (r < c) ? v * 10.f : ((r == c) ? -100.f : 0.f);
            A[e] = 1.f / (1.f + expf(-l2));
            part += sig;
            float a2 = sig * sig;
            A2s[e] = a2; mp[e] = a2;
        }
        red[t] = part; __syncthreads();
        for (int s = 128; s > 0; s >>= 1){ if (t < s) red[t] += red[t + s]; __syncthreads(); }
        if (t == 0) acc[2] = red[0];

        const float invf[10] = {0.f, 1.f, 0.5f, 1.6666667e-1f, 4.1666667e-2f,
                                8.3333333e-3f, 1.3888889e-3f, 1.9841270e-4f,
                                2.4801587e-5f, 2.7557319e-6f};
        float tr = 0.f;
        const int r = t >> 3, c0 = (t & 7) * 4;
        for (int n = 1; n <= 9; ++n){
            __syncthreads();
            if (t == 0){
                float s = 0.f;
                for (int k2 = 0; k2 < 32; ++k2) s += mp[k2 * 33];
                tr += s * invf[n];
            }
            if (n == 9) break;
            float av[4] = {0.f, 0.f, 0.f, 0.f};
            for (int k2 = 0; k2 < 32; ++k2){
                float m = mp[r * 32 + k2];
                #pragma unroll
                for (int q = 0; q < 4; ++q) av[q] = fmaf(m, A2s[k2 * 32 + c0 + q], av[q]);
            }
            __syncthreads();
            #pragma unroll
            for (int q = 0; q < 4; ++q) mp[r * 32 + c0 + q] = av[q];
        }
        if (t == 0) acc[3] = tr * tr;
        return;
    }
    for (int idx = blockIdx.x * 256 + threadIdx.x; idx < 299008; idx += 2048 * 256){
        int d = idx * 8;
        if (d < 2097152){                    // featbf: linear copy-convert
            f32x4 a0 = *(const f32x4*)&feat[d];
            f32x4 a1 = *(const f32x4*)&feat[d + 4];
            s16x8 v;
            #pragma unroll
            for (int e = 0; e < 4; ++e){ v[e] = f2bf(a0[e]); v[e + 4] = f2bf(a1[e]); }
            *(s16x8*)&featbf[d] = v;
            continue;
        }
        int s = d - 2097152;
        if (s < 262144){                     // enc_w1 [512][512] -> w1p
            int t2 = s >> 9, lane = (s & 511) >> 3;
            int kb = (t2 & 15) * 32 + (lane >> 4) * 8;
            int n  = (t2 >> 4) * 16 + (lane & 15);
            s16x8 v;
            #pragma unroll
            for (int e = 0; e < 8; ++e) v[e] = f2bf(ew1[(kb + e) * 512 + n]);
            *(s16x8*)&w1p[s] = v;
            continue;
        }
        s -= 262144;                         // enc_w2 [512][64] -> ew2p
        int t2 = s >> 9, lane = (s & 511) >> 3;
        int kb = (t2 & 15) * 32 + (lane >> 4) * 8;
        int n  = (t2 >> 4) * 16 + (lane & 15);
        s16x8 v;
        #pragma unroll
        for (int e = 0; e < 8; ++e) v[e] = f2bf(ew2[(kb + e) * 64 + n]);
        *(s16x8*)&ew2p[s] = v;
    }
}

// ---------------------------------------------------------------------------
// K_encf: blocks 0..255 = fused encoder (512 threads); blocks 256..895 =
// weight packing for mimech/decf overlapped on idle CUs.
// ---------------------------------------------------------------------------
__global__ __launch_bounds__(512) void k_encf(
    const short* __restrict__ featbf, const short* __restrict__ w1p,
    const float* __restrict__ eb1, const short* __restrict__ ew2p,
    const float* __restrict__ eb2, const float* __restrict__ eps,
    float* __restrict__ omean, float* __restrict__ ostd,
    float* __restrict__ zt, float* __restrict__ accg,
    const float* __restrict__ dw2, const float* __restrict__ mw1,
    const float* __restrict__ mw2, const float* __restrict__ dw1,
    short* __restrict__ dw2p, short* __restrict__ mw1p,
    short* __restrict__ mw2p, short* __restrict__ dw1p)
{
    __shared__ short hlds[8192];
    __shared__ float P[16][65];
    __shared__ float zs[16][33];
    __shared__ float red[512];
    const int t = threadIdx.x, lane = t & 63, wv = t >> 6;   // wv 0..7
    const int ml = lane & 15, kg = lane >> 4;

    if (blockIdx.x >= 256){
        // ---------------- weight packing (overlapped) ----------------
        for (int idx = (blockIdx.x - 256) * 512 + t; idx < 321536; idx += 640 * 512){
            int d = idx * 8;
            if (d < 262144){                 // dec_w2 [512][512] -> dw2p
                int s = d;
                int t2 = s >> 9, lane2 = (s & 511) >> 3;
                int kb = (t2 & 15) * 32 + (lane2 >> 4) * 8;
                int n  = (t2 >> 4) * 16 + (lane2 & 15);
                s16x8 v;
                #pragma unroll
                for (int e = 0; e < 8; ++e) v[e] = f2bf(dw2[(kb + e) * 512 + n]);
                *(s16x8*)&dw2p[s] = v;
                continue;
            }
            int s = d - 262144;
            if (s < 262144){                 // mech_w1 [32][32][256] -> mw1p
                int i = s >> 13, r2 = s & 8191;
                int nt = r2 >> 9, lane2 = (r2 & 511) >> 3;
                int kb = (lane2 >> 4) * 8;
                int n  = nt * 16 + (lane2 & 15);
                s16x8 v;
                #pragma unroll
                for (int e = 0; e < 8; ++e) v[e] = f2bf(mw1[i * 8192 + (kb + e) * 256 + n]);
                *(s16x8*)&mw1p[s] = v;
                continue;
            }
            s -= 262144;
            if (s < 2031616){                // mi_w2 [496][64][64] -> mw2p
                int p = s >> 12, r2 = s & 4095;
                int tt = r2 >> 9, lane2 = (r2 & 511) >> 3;
                int nb = tt >> 1, ks = tt & 1;
                int kb = ks * 32 + (lane2 >> 4) * 8;
                int col = nb * 16 + (lane2 & 15);
                s16x8 v;
                #pragma unroll
                for (int e = 0; e < 8; ++e) v[e] = f2bf(mw2[(size_t)p * 4096 + (kb + e) * 64 + col]);
                *(s16x8*)&mw2p[s] = v;
                continue;
            }
            s -= 2031616;                    // dec_w1 [32][512] -> dw1p
            int nt = s >> 9, lane2 = (s & 511) >> 3;
            int kb = (lane2 >> 4) * 8;
            int n  = nt * 16 + (lane2 & 15);
            s16x8 v;
            #pragma unroll
            for (int e = 0; e < 8; ++e) v[e] = f2bf(dw1[(kb + e) * 512 + n]);
            *(s16x8*)&dw1p[s] = v;
        }
        return;
    }

    // ---------------- encoder (champion shape, unchanged) ----------------
    const int b0 = blockIdx.x * 16;

    f32x4 acc1[4] = {};
    for (int kt = 0; kt < 16; ++kt){
        s16x8 a = *(const s16x8*)&featbf[(size_t)(b0 + ml) * 512 + kt * 32 + kg * 8];
        #pragma unroll
        for (int nf = 0; nf < 4; ++nf){
            s16x8 b = *(const s16x8*)&w1p[((wv * 4 + nf) * 16 + kt) * 512 + lane * 8];
            acc1[nf] = __builtin_amdgcn_mfma_f32_16x16x32_bf16(a, b, acc1[nf], 0, 0, 0);
        }
    }
    #pragma unroll
    for (int nf = 0; nf < 4; ++nf){
        int col = wv * 64 + nf * 16 + ml;
        float bv = eb1[col];
        #pragma unroll
        for (int r = 0; r < 4; ++r){
            int row = kg * 4 + r;
            int byte = (row * 1024 + col * 2) ^ ((row & 7) << 4);
            hlds[byte >> 1] = f2bf(leaky2(acc1[nf][r] + bv));
        }
    }
    __syncthreads();

    if (wv < 4){
        f32x4 acc2 = {};
        for (int kt = 0; kt < 16; ++kt){
            int byte = (ml * 1024 + kt * 64 + kg * 16) ^ ((ml & 7) << 4);
            s16x8 a = *(const s16x8*)((const char*)hlds + byte);
            s16x8 b = *(const s16x8*)&ew2p[(wv * 16 + kt) * 512 + lane * 8];
            acc2 = __builtin_amdgcn_mfma_f32_16x16x32_bf16(a, b, acc2, 0, 0, 0);
        }
        int col = wv * 16 + ml;
        float bv = eb2[col];
        #pragma unroll
        for (int r = 0; r < 4; ++r)
            P[kg * 4 + r][col] = acc2[r] + bv;
    }
    __syncthreads();
    float klp = 0.f;
    {
        int row = t >> 5, n = t & 31;
        float mean = P[row][n], ls = P[row][n + 32];
        float sd = expf(ls);
        size_t o = (size_t)(b0 + row) * 32 + n;
        float z = fmaf(sd, eps[o], mean);
        omean[o] = mean; ostd[o] = sd;
        zs[row][n] = z;
        klp = mean * mean + sd * sd - 2.f * ls - 1.f;
    }
    __syncthreads();
    {
        int n = t >> 4, row = t & 15;
        zt[(size_t)n * 4096 + b0 + row] = zs[row][n];
    }
    red[t] = klp; __syncthreads();
    for (int s = 256; s > 0; s >>= 1){ if (t < s) red[t] += red[t + s]; __syncthreads(); }
    if (t == 0) atomicAdd(accg + 0, red[0]);
}

// ---------------------------------------------------------------------------
// K_mimech: MI pair-MLPs (blocks 0..1983) + mech MLPs (1984..4031). UNCHANGED.
// ---------------------------------------------------------------------------
__global__ __launch_bounds__(256) void k_mimech(
    const float* __restrict__ zt,
    const float* __restrict__ w1g, const float* __restrict__ b1g,
    const short* __restrict__ w2p, const float* __restrict__ b2g,
    const float* __restrict__ w3g, float* __restrict__ macc,
    const float* __restrict__ A, const short* __restrict__ W1p,
    const float* __restrict__ mb1, const float* __restrict__ mw2,
    const float* __restrict__ mb2, float* __restrict__ out_zc)
{
    __shared__ float sA[32], sB1[256], sW2[256];
    const int t = threadIdx.x, lane = t & 63, wv = t >> 6;
    const int ml = lane & 15, kg = lane >> 4;
    if (blockIdx.x < 1984){
        const int p = blockIdx.x >> 2, bq = blockIdx.x & 3;
        int pi = 0, rem = p;
        while (rem >= 31 - pi){ rem -= 31 - pi; ++pi; }
        const int pj = pi + 1 + rem;

        const int zrow = wv * 16 + ml;
        const float* zi_b = zt + (size_t)pi * 4096 + bq * 1024 + zrow;
        const float* zj_b = zt + (size_t)pj * 4096 + bq * 1024 + zrow;

        f32x2 w10v[2][4], w11v[2][4], b1v[2][4];
        #pragma unroll
        for (int ks = 0; ks < 2; ++ks)
            #pragma unroll
            for (int q = 0; q < 4; ++q){
                int h = ks * 32 + kg * 8 + q * 2;
                w10v[ks][q] = *(const f32x2*)&w1g[p * 128 + h] * 0.6f;
                w11v[ks][q] = *(const f32x2*)&w1g[p * 128 + 64 + h] * 0.6f;
                b1v[ks][q]  = *(const f32x2*)&b1g[p * 64 + h] * 0.6f;
            }
        s16x8 bfr[4][2];
        f32x4 b2c[4];
        #pragma unroll
        for (int nb = 0; nb < 4; ++nb){
            float bv = b2g[p * 64 + nb * 16 + ml];
            b2c[nb][0] = bv; b2c[nb][1] = bv; b2c[nb][2] = bv; b2c[nb][3] = bv;
            #pragma unroll
            for (int ks = 0; ks < 2; ++ks)
                bfr[nb][ks] = *(const s16x8*)&w2p[(size_t)p * 4096 + (nb * 2 + ks) * 512 + lane * 8];
        }
        const f32x2 c23 = {0.66666669f, 0.66666669f};
        float slin[4] = {0.f, 0.f, 0.f, 0.f}, sabs[4] = {0.f, 0.f, 0.f, 0.f};
        #pragma unroll 1
        for (int tile = 0; tile < 16; ++tile){
            float zi_c = zi_b[tile * 64], zj_c = zj_b[tile * 64];
            f32x2 zi2 = {zi_c, zi_c}, zj2 = {zj_c, zj_c};
            s16x8 af0, af1;
            #pragma unroll
            for (int q = 0; q < 4; ++q){
                f32x2 m0 = __builtin_elementwise_fma(zi2, w10v[0][q],
                           __builtin_elementwise_fma(zj2, w11v[0][q], b1v[0][q]));
                m0 = __builtin_elementwise_fma(c23, __builtin_elementwise_abs(m0), m0);
                af0[q * 2] = f2bf(m0[0]); af0[q * 2 + 1] = f2bf(m0[1]);
                f32x2 m1 = __builtin_elementwise_fma(zi2, w10v[1][q],
                           __builtin_elementwise_fma(zj2, w11v[1][q], b1v[1][q]));
                m1 = __builtin_elementwise_fma(c23, __builtin_elementwise_abs(m1), m1);
                af1[q * 2] = f2bf(m1[0]); af1[q * 2 + 1] = f2bf(m1[1]);
            }
            #pragma unroll
            for (int nb = 0; nb < 4; ++nb){
                f32x4 d = __builtin_amdgcn_mfma_f32_16x16x32_bf16(af0, bfr[nb][0], b2c[nb], 0, 0, 0);
                d = __builtin_amdgcn_mfma_f32_16x16x32_bf16(af1, bfr[nb][1], d, 0, 0, 0);
                #pragma unroll
                for (int r2 = 0; r2 < 4; ++r2){
                    slin[nb] += d[r2];
                    sabs[nb] += fabsf(d[r2]);
                }
            }
        }
        float s = 0.f;
        #pragma unroll
        for (int nb = 0; nb < 4; ++nb){
            float w3 = w3g[p * 64 + nb * 16 + ml];
            s = fmaf(0.6f * w3, slin[nb], fmaf(0.4f * w3, sabs[nb], s));
        }
        #pragma unroll
        for (int off = 32; off; off >>= 1) s += __shfl_xor(s, off);
        if (lane == 0) atomicAdd(&macc[p], s);
    } else {
        const int bx = blockIdx.x - 1984;
        const int i = bx & 31;
        const int b0 = (bx >> 5) * 64 + wv * 16;
        if (t < 32) sA[t] = A[t * 32 + i];
        sB1[t] = mb1[i * 256 + t];
        sW2[t] = mw2[i * 256 + t];
        __syncthreads();
        float zv[8];
        #pragma unroll
        for (int q = 0; q < 8; ++q)
            zv[q] = zt[(size_t)(kg * 8 + q) * 4096 + b0 + ml];
        s16x8 af;
        #pragma unroll
        for (int q = 0; q < 8; ++q)
            af[q] = f2bf(zv[q] * sA[kg * 8 + q]);
        float s[4] = {0.f, 0.f, 0.f, 0.f};
        #pragma unroll
        for (int nt = 0; nt < 16; ++nt){
            s16x8 bf = *(const s16x8*)&W1p[i * 8192 + nt * 512 + lane * 8];
            int col = nt * 16 + ml;
            float b1e = sB1[col], w2v = sW2[col];
            f32x4 d;
            d[0] = b1e; d[1] = b1e; d[2] = b1e; d[3] = b1e;
            d = __builtin_amdgcn_mfma_f32_16x16x32_bf16(af, bf, d, 0, 0, 0);
            float w2a = 0.6f * w2v, w2b = 0.4f * w2v;
            #pragma unroll
            for (int r = 0; r < 4; ++r)
                s[r] = fmaf(w2a, d[r], fmaf(w2b, fabsf(d[r]), s[r]));
        }
        #pragma unroll
        for (int off = 1; off < 16; off <<= 1)
            #pragma unroll
            for (int r = 0; r < 4; ++r) s[r] += __shfl_xor(s[r], off);
        if (ml == 0){
            float bb = mb2[i];
            #pragma unroll
            for (int r = 0; r < 4; ++r){
                int b = b0 + kg * 4 + r;
                out_zc[(size_t)b * 32 + i] = s[r] + bb;
            }
        }
    }
}

// ---------------------------------------------------------------------------
// K_decf: fused decoder, 16-row blocks, grid (256,4) = 1024 blocks.
// Last finishing block (done-counter) also computes the final scalar losses
// (replaces the separate k_final dispatch; no spinning anywhere).
// ---------------------------------------------------------------------------
__global__ __launch_bounds__(256) void k_decf(
    const float* __restrict__ zc, const short* __restrict__ dw1p,
    const float* __restrict__ db1, const short* __restrict__ dw2p,
    const float* __restrict__ db2, const float* __restrict__ feat,
    float* __restrict__ recon, float* __restrict__ accg,
    unsigned* __restrict__ done, const float* __restrict__ lw,
    const float* __restrict__ b3, float* __restrict__ outs)
{
    __shared__ short dlds[8192];           // 16 x 512 bf16, XOR-swizzled
    __shared__ float red[256];
    __shared__ int lastflag;
    const int t = threadIdx.x, lane = t & 63, wv = t >> 6;
    const int ml = lane & 15, kg = lane >> 4;
    const int b0 = blockIdx.x * 16;
    const int c0 = blockIdx.y * 128;

    s16x8 af;
    {
        int row = b0 + ml;
        f32x4 z0 = *(const f32x4*)&zc[(size_t)row * 32 + kg * 8];
        f32x4 z1 = *(const f32x4*)&zc[(size_t)row * 32 + kg * 8 + 4];
        #pragma unroll
        for (int e = 0; e < 4; ++e){
            af[e] = f2bf(z0[e]);
            af[e + 4] = f2bf(z1[e]);
        }
    }
    #pragma unroll
    for (int nf = 0; nf < 8; ++nf){
        int nt = wv * 8 + nf;
        s16x8 bf = *(const s16x8*)&dw1p[nt * 512 + lane * 8];
        int col = nt * 16 + ml;
        float b1e = db1[col];
        f32x4 c; c[0] = b1e; c[1] = b1e; c[2] = b1e; c[3] = b1e;
        f32x4 d = __builtin_amdgcn_mfma_f32_16x16x32_bf16(af, bf, c, 0, 0, 0);
        #pragma unroll
        for (int r = 0; r < 4; ++r){
            int row = kg * 4 + r;
            int byte = (row * 1024 + col * 2) ^ ((row & 7) << 4);
            dlds[byte >> 1] = f2bf(leaky2(d[r]));
        }
    }
    __syncthreads();

    f32x4 acc[2] = {};
    for (int kt = 0; kt < 16; ++kt){
        int byte = (ml * 1024 + kt * 64 + kg * 16) ^ ((ml & 7) << 4);
        s16x8 a = *(const s16x8*)((const char*)dlds + byte);
        #pragma unroll
        for (int j = 0; j < 2; ++j){
            int nt = (c0 >> 4) + wv * 2 + j;
            s16x8 b = *(const s16x8*)&dw2p[(nt * 16 + kt) * 512 + lane * 8];
            acc[j] = __builtin_amdgcn_mfma_f32_16x16x32_bf16(a, b, acc[j], 0, 0, 0);
        }
    }
    float lsum = 0.f;
    #pragma unroll
    for (int j = 0; j < 2; ++j){
        int col = c0 + (wv * 2 + j) * 16 + ml;
        float bv = db2[col];
        #pragma unroll
        for (int r = 0; r < 4; ++r){
            int row = b0 + kg * 4 + r;
            float v = acc[j][r] + bv;
            float d = v - feat[(size_t)row * 512 + col];
            lsum = fmaf(d, d, lsum);
            recon[(size_t)row * 512 + col] = v;
        }
    }
    red[t] = lsum; __syncthreads();
    for (int s = 128; s > 0; s >>= 1){ if (t < s) red[t] += red[t + s]; __syncthreads(); }
    if (t == 0){
        atomicAdd(accg + 1, red[0]);
        __threadfence();
        unsigned prev = atomicAdd(done, 1u);
        lastflag = (prev == 1023u);
    }
    __syncthreads();
    if (!lastflag) return;

    // ---- final scalar losses (last block only; all inputs complete) ----
    __threadfence();
    float c = 0.f;
    for (int q = t; q < 496; q += 256){
        int pi = 0, rem = q;
        while (rem >= 31 - pi){ rem -= 31 - pi; ++pi; }
        int pj = pi + 1 + rem;
        float est = accg[4 + q] * (1.f / 4096.f) + b3[q];
        float w = 1.f / (1.f + expf(-lw[pi * 32 + pj]));
        c = fmaf(w, est, c);
    }
    red[t] = c; __syncthreads();
    for (int s = 128; s > 0; s >>= 1){ if (t < s) red[t] += red[t + s]; __syncthreads(); }
    if (t == 0){
        float mi    = red[0];
        float recon_l = atomicAdd(accg + 1, 0.f) * (1.f / (4096.f * 512.f));
        float kl    = 0.5f * accg[0] * (1.f / 4096.f);
        float sp    = accg[2], dag = accg[3];
        outs[0] = recon_l + kl + 0.1f * sp + 0.01f * mi + dag;
        outs[1] = recon_l; outs[2] = kl; outs[3] = sp; outs[4] = mi; outs[5] = dag;
    }
}

// ---------------------------------------------------------------------------
extern "C" void kernel_launch(void* const* d_in, const int* in_sizes, int n_in,
                              void* d_out, int out_size, void* d_ws, size_t ws_size,
                              hipStream_t stream)
{
    const float* features = (const float*)d_in[0];
    const float* eps      = (const float*)d_in[1];
    const float* enc_w1   = (const float*)d_in[2];
    const float* enc_b1   = (const float*)d_in[3];
    const float* enc_w2   = (const float*)d_in[4];
    const float* enc_b2   = (const float*)d_in[5];
    const float* log_w    = (const float*)d_in[6];
    const float* mech_w1  = (const float*)d_in[7];
    const float* mech_b1  = (const float*)d_in[8];
    const float* mech_w2  = (const float*)d_in[9];
    const float* mech_b2  = (const float*)d_in[10];
    const float* dec_w1   = (const float*)d_in[11];
    const float* dec_b1   = (const float*)d_in[12];
    const float* dec_w2   = (const float*)d_in[13];
    const float* dec_b2   = (const float*)d_in[14];
    const float* mi_w1    = (const float*)d_in[15];
    const float* mi_b1    = (const float*)d_in[16];
    const float* mi_w2    = (const float*)d_in[17];
    const float* mi_b2    = (const float*)d_in[18];
    const float* mi_w3    = (const float*)d_in[19];
    const float* mi_b3    = (const float*)d_in[20];

    float* W      = (float*)d_ws;
    float* zt     = W;                         // [32][4096] f32
    float* Abuf   = W + 262144;                // 1024
    float* accums = W + 263168;                // 512 ([501] = decf done counter)
    short* w1p    = (short*)(W + 263680);      // 262144 sh
    short* ew2p   = (short*)(W + 394752);      // 32768 sh
    short* dw2p   = (short*)(W + 411136);      // 262144 sh
    short* mw1p   = (short*)(W + 542208);      // 262144 sh
    short* mw2p   = (short*)(W + 673280);      // 2031616 sh
    short* dw1p   = (short*)(W + 1689088);     // 16384 sh
    float* out    = (float*)d_out;
    short* featbf = (short*)(out + 393216);    // scratch in dead recon region

    k_cvt<<<2049, 256, 0, stream>>>(features, enc_w1, enc_w2,
                                    featbf, w1p, ew2p, log_w, Abuf, accums);
    k_encf<<<896, 512, 0, stream>>>(featbf, w1p, enc_b1, ew2p, enc_b2, eps,
                                    out + 131072, out + 262144, zt, accums,
                                    dec_w2, mech_w1, mi_w2, dec_w1,
                                    dw2p, mw1p, mw2p, dw1p);
    k_mimech<<<4032, 256, 0, stream>>>(zt, mi_w1, mi_b1, mw2p, mi_b2, mi_w3, accums + 4,
                                       Abuf, mw1p, mech_b1, mech_w2, mech_b2, out);
    k_decf<<<dim3(256, 4), 256, 0, stream>>>(out, dw1p, dec_b1, dw2p, dec_b2, features,
                                             out + 393216, accums,
                                             (unsigned*)(accums + 501),
                                             log_w, mi_b3, out + 2490368);
}

// Round 20
// 111.150 us; speedup vs baseline: 1.0922x; 1.0922x over previous
//
#include <hip/hip_runtime.h>
#include <hip/hip_bf16.h>

typedef float f32x4 __attribute__((ext_vector_type(4)));
typedef float f32x2 __attribute__((ext_vector_type(2)));
typedef short s16x8 __attribute__((ext_vector_type(8)));

__device__ __forceinline__ float leaky2(float x){ return fmaf(0.4f, fabsf(x), 0.6f * x); }

__device__ __forceinline__ short f2bf(float f){
    return __builtin_bit_cast(short, __float2bfloat16(f));
}

// ---------------------------------------------------------------------------
// K_cvt (lite): packs featbf + w1p + ew2p. Block 2048 zeroes accums + setup.
// ---------------------------------------------------------------------------
__global__ __launch_bounds__(256) void k_cvt(
    const float* __restrict__ feat, const float* __restrict__ ew1,
    const float* __restrict__ ew2,
    short* __restrict__ featbf, short* __restrict__ w1p,
    short* __restrict__ ew2p,
    const float* __restrict__ lw, float* __restrict__ A,
    float* __restrict__ acc)
{
    if (blockIdx.x >= 2048){
        __shared__ float A2s[1024], mp[1024], red[256];
        const int t = threadIdx.x;
        acc[t] = 0.f;
        acc[t + 256] = 0.f;
        float part = 0.f;
        #pragma unroll
        for (int q = 0; q < 4; ++q){
            int e = t * 4 + q;
            int r = e >> 5, c = e & 31;
            float v = lw[e];
            float sig = 1.f / (1.f + expf(-v));
            float l2 = (r < c) ? v * 10.f : ((r == c) ? -100.f : 0.f);
            A[e] = 1.f / (1.f + expf(-l2));
            part += sig;
            float a2 = sig * sig;
            A2s[e] = a2; mp[e] = a2;
        }
        red[t] = part; __syncthreads();
        for (int s = 128; s > 0; s >>= 1){ if (t < s) red[t] += red[t + s]; __syncthreads(); }
        if (t == 0) acc[2] = red[0];

        const float invf[10] = {0.f, 1.f, 0.5f, 1.6666667e-1f, 4.1666667e-2f,
                                8.3333333e-3f, 1.3888889e-3f, 1.9841270e-4f,
                                2.4801587e-5f, 2.7557319e-6f};
        float tr = 0.f;
        const int r = t >> 3, c0 = (t & 7) * 4;
        for (int n = 1; n <= 9; ++n){
            __syncthreads();
            if (t == 0){
                float s = 0.f;
                for (int k2 = 0; k2 < 32; ++k2) s += mp[k2 * 33];
                tr += s * invf[n];
            }
            if (n == 9) break;
            float av[4] = {0.f, 0.f, 0.f, 0.f};
            for (int k2 = 0; k2 < 32; ++k2){
                float m = mp[r * 32 + k2];
                #pragma unroll
                for (int q = 0; q < 4; ++q) av[q] = fmaf(m, A2s[k2 * 32 + c0 + q], av[q]);
            }
            __syncthreads();
            #pragma unroll
            for (int q = 0; q < 4; ++q) mp[r * 32 + c0 + q] = av[q];
        }
        if (t == 0) acc[3] = tr * tr;
        return;
    }
    for (int idx = blockIdx.x * 256 + threadIdx.x; idx < 299008; idx += 2048 * 256){
        int d = idx * 8;
        if (d < 2097152){                    // featbf: linear copy-convert
            f32x4 a0 = *(const f32x4*)&feat[d];
            f32x4 a1 = *(const f32x4*)&feat[d + 4];
            s16x8 v;
            #pragma unroll
            for (int e = 0; e < 4; ++e){ v[e] = f2bf(a0[e]); v[e + 4] = f2bf(a1[e]); }
            *(s16x8*)&featbf[d] = v;
            continue;
        }
        int s = d - 2097152;
        if (s < 262144){                     // enc_w1 [512][512] -> w1p
            int t2 = s >> 9, lane = (s & 511) >> 3;
            int kb = (t2 & 15) * 32 + (lane >> 4) * 8;
            int n  = (t2 >> 4) * 16 + (lane & 15);
            s16x8 v;
            #pragma unroll
            for (int e = 0; e < 8; ++e) v[e] = f2bf(ew1[(kb + e) * 512 + n]);
            *(s16x8*)&w1p[s] = v;
            continue;
        }
        s -= 262144;                         // enc_w2 [512][64] -> ew2p
        int t2 = s >> 9, lane = (s & 511) >> 3;
        int kb = (t2 & 15) * 32 + (lane >> 4) * 8;
        int n  = (t2 >> 4) * 16 + (lane & 15);
        s16x8 v;
        #pragma unroll
        for (int e = 0; e < 8; ++e) v[e] = f2bf(ew2[(kb + e) * 64 + n]);
        *(s16x8*)&ew2p[s] = v;
    }
}

// ---------------------------------------------------------------------------
// K_encf: blocks 0..255 = fused encoder (512 threads); blocks 256..895 =
// weight packing for mimech/decf overlapped on idle CUs.
// ---------------------------------------------------------------------------
__global__ __launch_bounds__(512) void k_encf(
    const short* __restrict__ featbf, const short* __restrict__ w1p,
    const float* __restrict__ eb1, const short* __restrict__ ew2p,
    const float* __restrict__ eb2, const float* __restrict__ eps,
    float* __restrict__ omean, float* __restrict__ ostd,
    float* __restrict__ zt, float* __restrict__ accg,
    const float* __restrict__ dw2, const float* __restrict__ mw1,
    const float* __restrict__ mw2, const float* __restrict__ dw1,
    short* __restrict__ dw2p, short* __restrict__ mw1p,
    short* __restrict__ mw2p, short* __restrict__ dw1p)
{
    __shared__ short hlds[8192];
    __shared__ float P[16][65];
    __shared__ float zs[16][33];
    __shared__ float red[512];
    const int t = threadIdx.x, lane = t & 63, wv = t >> 6;   // wv 0..7
    const int ml = lane & 15, kg = lane >> 4;

    if (blockIdx.x >= 256){
        // ---------------- weight packing (overlapped) ----------------
        for (int idx = (blockIdx.x - 256) * 512 + t; idx < 321536; idx += 640 * 512){
            int d = idx * 8;
            if (d < 262144){                 // dec_w2 [512][512] -> dw2p
                int s = d;
                int t2 = s >> 9, lane2 = (s & 511) >> 3;
                int kb = (t2 & 15) * 32 + (lane2 >> 4) * 8;
                int n  = (t2 >> 4) * 16 + (lane2 & 15);
                s16x8 v;
                #pragma unroll
                for (int e = 0; e < 8; ++e) v[e] = f2bf(dw2[(kb + e) * 512 + n]);
                *(s16x8*)&dw2p[s] = v;
                continue;
            }
            int s = d - 262144;
            if (s < 262144){                 // mech_w1 [32][32][256] -> mw1p
                int i = s >> 13, r2 = s & 8191;
                int nt = r2 >> 9, lane2 = (r2 & 511) >> 3;
                int kb = (lane2 >> 4) * 8;
                int n  = nt * 16 + (lane2 & 15);
                s16x8 v;
                #pragma unroll
                for (int e = 0; e < 8; ++e) v[e] = f2bf(mw1[i * 8192 + (kb + e) * 256 + n]);
                *(s16x8*)&mw1p[s] = v;
                continue;
            }
            s -= 262144;
            if (s < 2031616){                // mi_w2 [496][64][64] -> mw2p
                int p = s >> 12, r2 = s & 4095;
                int tt = r2 >> 9, lane2 = (r2 & 511) >> 3;
                int nb = tt >> 1, ks = tt & 1;
                int kb = ks * 32 + (lane2 >> 4) * 8;
                int col = nb * 16 + (lane2 & 15);
                s16x8 v;
                #pragma unroll
                for (int e = 0; e < 8; ++e) v[e] = f2bf(mw2[(size_t)p * 4096 + (kb + e) * 64 + col]);
                *(s16x8*)&mw2p[s] = v;
                continue;
            }
            s -= 2031616;                    // dec_w1 [32][512] -> dw1p
            int nt = s >> 9, lane2 = (s & 511) >> 3;
            int kb = (lane2 >> 4) * 8;
            int n  = nt * 16 + (lane2 & 15);
            s16x8 v;
            #pragma unroll
            for (int e = 0; e < 8; ++e) v[e] = f2bf(dw1[(kb + e) * 512 + n]);
            *(s16x8*)&dw1p[s] = v;
        }
        return;
    }

    // ---------------- encoder (champion shape, unchanged) ----------------
    const int b0 = blockIdx.x * 16;

    f32x4 acc1[4] = {};
    for (int kt = 0; kt < 16; ++kt){
        s16x8 a = *(const s16x8*)&featbf[(size_t)(b0 + ml) * 512 + kt * 32 + kg * 8];
        #pragma unroll
        for (int nf = 0; nf < 4; ++nf){
            s16x8 b = *(const s16x8*)&w1p[((wv * 4 + nf) * 16 + kt) * 512 + lane * 8];
            acc1[nf] = __builtin_amdgcn_mfma_f32_16x16x32_bf16(a, b, acc1[nf], 0, 0, 0);
        }
    }
    #pragma unroll
    for (int nf = 0; nf < 4; ++nf){
        int col = wv * 64 + nf * 16 + ml;
        float bv = eb1[col];
        #pragma unroll
        for (int r = 0; r < 4; ++r){
            int row = kg * 4 + r;
            int byte = (row * 1024 + col * 2) ^ ((row & 7) << 4);
            hlds[byte >> 1] = f2bf(leaky2(acc1[nf][r] + bv));
        }
    }
    __syncthreads();

    if (wv < 4){
        f32x4 acc2 = {};
        for (int kt = 0; kt < 16; ++kt){
            int byte = (ml * 1024 + kt * 64 + kg * 16) ^ ((ml & 7) << 4);
            s16x8 a = *(const s16x8*)((const char*)hlds + byte);
            s16x8 b = *(const s16x8*)&ew2p[(wv * 16 + kt) * 512 + lane * 8];
            acc2 = __builtin_amdgcn_mfma_f32_16x16x32_bf16(a, b, acc2, 0, 0, 0);
        }
        int col = wv * 16 + ml;
        float bv = eb2[col];
        #pragma unroll
        for (int r = 0; r < 4; ++r)
            P[kg * 4 + r][col] = acc2[r] + bv;
    }
    __syncthreads();
    float klp = 0.f;
    {
        int row = t >> 5, n = t & 31;
        float mean = P[row][n], ls = P[row][n + 32];
        float sd = expf(ls);
        size_t o = (size_t)(b0 + row) * 32 + n;
        float z = fmaf(sd, eps[o], mean);
        omean[o] = mean; ostd[o] = sd;
        zs[row][n] = z;
        klp = mean * mean + sd * sd - 2.f * ls - 1.f;
    }
    __syncthreads();
    {
        int n = t >> 4, row = t & 15;
        zt[(size_t)n * 4096 + b0 + row] = zs[row][n];
    }
    red[t] = klp; __syncthreads();
    for (int s = 256; s > 0; s >>= 1){ if (t < s) red[t] += red[t + s]; __syncthreads(); }
    if (t == 0) atomicAdd(accg + 0, red[0]);
}

// ---------------------------------------------------------------------------
// K_mimech: MI pair-MLPs (blocks 0..1983) + mech MLPs (1984..4031). UNCHANGED.
// ---------------------------------------------------------------------------
__global__ __launch_bounds__(256) void k_mimech(
    const float* __restrict__ zt,
    const float* __restrict__ w1g, const float* __restrict__ b1g,
    const short* __restrict__ w2p, const float* __restrict__ b2g,
    const float* __restrict__ w3g, float* __restrict__ macc,
    const float* __restrict__ A, const short* __restrict__ W1p,
    const float* __restrict__ mb1, const float* __restrict__ mw2,
    const float* __restrict__ mb2, float* __restrict__ out_zc)
{
    __shared__ float sA[32], sB1[256], sW2[256];
    const int t = threadIdx.x, lane = t & 63, wv = t >> 6;
    const int ml = lane & 15, kg = lane >> 4;
    if (blockIdx.x < 1984){
        const int p = blockIdx.x >> 2, bq = blockIdx.x & 3;
        int pi = 0, rem = p;
        while (rem >= 31 - pi){ rem -= 31 - pi; ++pi; }
        const int pj = pi + 1 + rem;

        const int zrow = wv * 16 + ml;
        const float* zi_b = zt + (size_t)pi * 4096 + bq * 1024 + zrow;
        const float* zj_b = zt + (size_t)pj * 4096 + bq * 1024 + zrow;

        f32x2 w10v[2][4], w11v[2][4], b1v[2][4];
        #pragma unroll
        for (int ks = 0; ks < 2; ++ks)
            #pragma unroll
            for (int q = 0; q < 4; ++q){
                int h = ks * 32 + kg * 8 + q * 2;
                w10v[ks][q] = *(const f32x2*)&w1g[p * 128 + h] * 0.6f;
                w11v[ks][q] = *(const f32x2*)&w1g[p * 128 + 64 + h] * 0.6f;
                b1v[ks][q]  = *(const f32x2*)&b1g[p * 64 + h] * 0.6f;
            }
        s16x8 bfr[4][2];
        f32x4 b2c[4];
        #pragma unroll
        for (int nb = 0; nb < 4; ++nb){
            float bv = b2g[p * 64 + nb * 16 + ml];
            b2c[nb][0] = bv; b2c[nb][1] = bv; b2c[nb][2] = bv; b2c[nb][3] = bv;
            #pragma unroll
            for (int ks = 0; ks < 2; ++ks)
                bfr[nb][ks] = *(const s16x8*)&w2p[(size_t)p * 4096 + (nb * 2 + ks) * 512 + lane * 8];
        }
        const f32x2 c23 = {0.66666669f, 0.66666669f};
        float slin[4] = {0.f, 0.f, 0.f, 0.f}, sabs[4] = {0.f, 0.f, 0.f, 0.f};
        #pragma unroll 1
        for (int tile = 0; tile < 16; ++tile){
            float zi_c = zi_b[tile * 64], zj_c = zj_b[tile * 64];
            f32x2 zi2 = {zi_c, zi_c}, zj2 = {zj_c, zj_c};
            s16x8 af0, af1;
            #pragma unroll
            for (int q = 0; q < 4; ++q){
                f32x2 m0 = __builtin_elementwise_fma(zi2, w10v[0][q],
                           __builtin_elementwise_fma(zj2, w11v[0][q], b1v[0][q]));
                m0 = __builtin_elementwise_fma(c23, __builtin_elementwise_abs(m0), m0);
                af0[q * 2] = f2bf(m0[0]); af0[q * 2 + 1] = f2bf(m0[1]);
                f32x2 m1 = __builtin_elementwise_fma(zi2, w10v[1][q],
                           __builtin_elementwise_fma(zj2, w11v[1][q], b1v[1][q]));
                m1 = __builtin_elementwise_fma(c23, __builtin_elementwise_abs(m1), m1);
                af1[q * 2] = f2bf(m1[0]); af1[q * 2 + 1] = f2bf(m1[1]);
            }
            #pragma unroll
            for (int nb = 0; nb < 4; ++nb){
                f32x4 d = __builtin_amdgcn_mfma_f32_16x16x32_bf16(af0, bfr[nb][0], b2c[nb], 0, 0, 0);
                d = __builtin_amdgcn_mfma_f32_16x16x32_bf16(af1, bfr[nb][1], d, 0, 0, 0);
                #pragma unroll
                for (int r2 = 0; r2 < 4; ++r2){
                    slin[nb] += d[r2];
                    sabs[nb] += fabsf(d[r2]);
                }
            }
        }
        float s = 0.f;
        #pragma unroll
        for (int nb = 0; nb < 4; ++nb){
            float w3 = w3g[p * 64 + nb * 16 + ml];
            s = fmaf(0.6f * w3, slin[nb], fmaf(0.4f * w3, sabs[nb], s));
        }
        #pragma unroll
        for (int off = 32; off; off >>= 1) s += __shfl_xor(s, off);
        if (lane == 0) atomicAdd(&macc[p], s);
    } else {
        const int bx = blockIdx.x - 1984;
        const int i = bx & 31;
        const int b0 = (bx >> 5) * 64 + wv * 16;
        if (t < 32) sA[t] = A[t * 32 + i];
        sB1[t] = mb1[i * 256 + t];
        sW2[t] = mw2[i * 256 + t];
        __syncthreads();
        float zv[8];
        #pragma unroll
        for (int q = 0; q < 8; ++q)
            zv[q] = zt[(size_t)(kg * 8 + q) * 4096 + b0 + ml];
        s16x8 af;
        #pragma unroll
        for (int q = 0; q < 8; ++q)
            af[q] = f2bf(zv[q] * sA[kg * 8 + q]);
        float s[4] = {0.f, 0.f, 0.f, 0.f};
        #pragma unroll
        for (int nt = 0; nt < 16; ++nt){
            s16x8 bf = *(const s16x8*)&W1p[i * 8192 + nt * 512 + lane * 8];
            int col = nt * 16 + ml;
            float b1e = sB1[col], w2v = sW2[col];
            f32x4 d;
            d[0] = b1e; d[1] = b1e; d[2] = b1e; d[3] = b1e;
            d = __builtin_amdgcn_mfma_f32_16x16x32_bf16(af, bf, d, 0, 0, 0);
            float w2a = 0.6f * w2v, w2b = 0.4f * w2v;
            #pragma unroll
            for (int r = 0; r < 4; ++r)
                s[r] = fmaf(w2a, d[r], fmaf(w2b, fabsf(d[r]), s[r]));
        }
        #pragma unroll
        for (int off = 1; off < 16; off <<= 1)
            #pragma unroll
            for (int r = 0; r < 4; ++r) s[r] += __shfl_xor(s[r], off);
        if (ml == 0){
            float bb = mb2[i];
            #pragma unroll
            for (int r = 0; r < 4; ++r){
                int b = b0 + kg * 4 + r;
                out_zc[(size_t)b * 32 + i] = s[r] + bb;
            }
        }
    }
}

// ---------------------------------------------------------------------------
// K_decf: fused decoder, 16-row blocks, grid (256,4) = 1024 blocks. UNCHANGED.
// ---------------------------------------------------------------------------
__global__ __launch_bounds__(256) void k_decf(
    const float* __restrict__ zc, const short* __restrict__ dw1p,
    const float* __restrict__ db1, const short* __restrict__ dw2p,
    const float* __restrict__ db2, const float* __restrict__ feat,
    float* __restrict__ recon, float* __restrict__ accg)
{
    __shared__ short dlds[8192];           // 16 x 512 bf16, XOR-swizzled
    __shared__ float red[256];
    const int t = threadIdx.x, lane = t & 63, wv = t >> 6;
    const int ml = lane & 15, kg = lane >> 4;
    const int b0 = blockIdx.x * 16;
    const int c0 = blockIdx.y * 128;

    s16x8 af;
    {
        int row = b0 + ml;
        f32x4 z0 = *(const f32x4*)&zc[(size_t)row * 32 + kg * 8];
        f32x4 z1 = *(const f32x4*)&zc[(size_t)row * 32 + kg * 8 + 4];
        #pragma unroll
        for (int e = 0; e < 4; ++e){
            af[e] = f2bf(z0[e]);
            af[e + 4] = f2bf(z1[e]);
        }
    }
    #pragma unroll
    for (int nf = 0; nf < 8; ++nf){
        int nt = wv * 8 + nf;
        s16x8 bf = *(const s16x8*)&dw1p[nt * 512 + lane * 8];
        int col = nt * 16 + ml;
        float b1e = db1[col];
        f32x4 c; c[0] = b1e; c[1] = b1e; c[2] = b1e; c[3] = b1e;
        f32x4 d = __builtin_amdgcn_mfma_f32_16x16x32_bf16(af, bf, c, 0, 0, 0);
        #pragma unroll
        for (int r = 0; r < 4; ++r){
            int row = kg * 4 + r;
            int byte = (row * 1024 + col * 2) ^ ((row & 7) << 4);
            dlds[byte >> 1] = f2bf(leaky2(d[r]));
        }
    }
    __syncthreads();

    f32x4 acc[2] = {};
    for (int kt = 0; kt < 16; ++kt){
        int byte = (ml * 1024 + kt * 64 + kg * 16) ^ ((ml & 7) << 4);
        s16x8 a = *(const s16x8*)((const char*)dlds + byte);
        #pragma unroll
        for (int j = 0; j < 2; ++j){
            int nt = (c0 >> 4) + wv * 2 + j;
            s16x8 b = *(const s16x8*)&dw2p[(nt * 16 + kt) * 512 + lane * 8];
            acc[j] = __builtin_amdgcn_mfma_f32_16x16x32_bf16(a, b, acc[j], 0, 0, 0);
        }
    }
    float lsum = 0.f;
    #pragma unroll
    for (int j = 0; j < 2; ++j){
        int col = c0 + (wv * 2 + j) * 16 + ml;
        float bv = db2[col];
        #pragma unroll
        for (int r = 0; r < 4; ++r){
            int row = b0 + kg * 4 + r;
            float v = acc[j][r] + bv;
            float d = v - feat[(size_t)row * 512 + col];
            lsum = fmaf(d, d, lsum);
            recon[(size_t)row * 512 + col] = v;
        }
    }
    red[t] = lsum; __syncthreads();
    for (int s = 128; s > 0; s >>= 1){ if (t < s) red[t] += red[t + s]; __syncthreads(); }
    if (t == 0) atomicAdd(accg + 1, red[0]);
}

// ---------------------------------------------------------------------------
// K_final
// ---------------------------------------------------------------------------
__global__ void k_final(const float* __restrict__ acc, const float* __restrict__ lw,
                        const float* __restrict__ b3, float* __restrict__ outs)
{
    __shared__ float red[512];
    int t = threadIdx.x;
    float c = 0.f;
    if (t < 496){
        int pi = 0, rem = t;
        while (rem >= 31 - pi){ rem -= 31 - pi; ++pi; }
        int pj = pi + 1 + rem;
        float est = acc[4 + t] * (1.f / 4096.f) + b3[t];
        float w = 1.f / (1.f + expf(-lw[pi * 32 + pj]));
        c = w * est;
    }
    red[t] = c; __syncthreads();
    for (int s = 256; s > 0; s >>= 1){ if (t < s) red[t] += red[t + s]; __syncthreads(); }
    if (t == 0){
        float mi    = red[0];
        float recon = acc[1] * (1.f / (4096.f * 512.f));
        float kl    = 0.5f * acc[0] * (1.f / 4096.f);
        float sp    = acc[2], dag = acc[3];
        outs[0] = recon + kl + 0.1f * sp + 0.01f * mi + dag;
        outs[1] = recon; outs[2] = kl; outs[3] = sp; outs[4] = mi; outs[5] = dag;
    }
}

// ---------------------------------------------------------------------------
extern "C" void kernel_launch(void* const* d_in, const int* in_sizes, int n_in,
                              void* d_out, int out_size, void* d_ws, size_t ws_size,
                              hipStream_t stream)
{
    const float* features = (const float*)d_in[0];
    const float* eps      = (const float*)d_in[1];
    const float* enc_w1   = (const float*)d_in[2];
    const float* enc_b1   = (const float*)d_in[3];
    const float* enc_w2   = (const float*)d_in[4];
    const float* enc_b2   = (const float*)d_in[5];
    const float* log_w    = (const float*)d_in[6];
    const float* mech_w1  = (const float*)d_in[7];
    const float* mech_b1  = (const float*)d_in[8];
    const float* mech_w2  = (const float*)d_in[9];
    const float* mech_b2  = (const float*)d_in[10];
    const float* dec_w1   = (const float*)d_in[11];
    const float* dec_b1   = (const float*)d_in[12];
    const float* dec_w2   = (const float*)d_in[13];
    const float* dec_b2   = (const float*)d_in[14];
    const float* mi_w1    = (const float*)d_in[15];
    const float* mi_b1    = (const float*)d_in[16];
    const float* mi_w2    = (const float*)d_in[17];
    const float* mi_b2    = (const float*)d_in[18];
    const float* mi_w3    = (const float*)d_in[19];
    const float* mi_b3    = (const float*)d_in[20];

    float* W      = (float*)d_ws;
    float* zt     = W;                         // [32][4096] f32
    float* Abuf   = W + 262144;                // 1024
    float* accums = W + 263168;                // 512
    short* w1p    = (short*)(W + 263680);      // 262144 sh
    short* ew2p   = (short*)(W + 394752);      // 32768 sh
    short* dw2p   = (short*)(W + 411136);      // 262144 sh
    short* mw1p   = (short*)(W + 542208);      // 262144 sh
    short* mw2p   = (short*)(W + 673280);      // 2031616 sh
    short* dw1p   = (short*)(W + 1689088);     // 16384 sh
    float* out    = (float*)d_out;
    short* featbf = (short*)(out + 393216);    // scratch in dead recon region

    k_cvt<<<2049, 256, 0, stream>>>(features, enc_w1, enc_w2,
                                    featbf, w1p, ew2p, log_w, Abuf, accums);
    k_encf<<<896, 512, 0, stream>>>(featbf, w1p, enc_b1, ew2p, enc_b2, eps,
                                    out + 131072, out + 262144, zt, accums,
                                    dec_w2, mech_w1, mi_w2, dec_w1,
                                    dw2p, mw1p, mw2p, dw1p);
    k_mimech<<<4032, 256, 0, stream>>>(zt, mi_w1, mi_b1, mw2p, mi_b2, mi_w3, accums + 4,
                                       Abuf, mw1p, mech_b1, mech_w2, mech_b2, out);
    k_decf<<<dim3(256, 4), 256, 0, stream>>>(out, dw1p, dec_b1, dw2p, dec_b2, features,
                                             out + 393216, accums);
    k_final<<<1, 512, 0, stream>>>(accums, log_w, mi_b3, out + 2490368);
}